// Round 1
// baseline (354.327 us; speedup 1.0000x reference)
//
#include <hip/hip_runtime.h>

#define IN_C 128
#define OUT_C 256
#define LN_EPS 1e-5f
#define MTILE 16
#define SCAN_BLK 1024

// ---------- degree / dinv ----------
__global__ __launch_bounds__(256) void k_init(int* __restrict__ deg, int* __restrict__ cursor, int n) {
    int i = blockIdx.x * 256 + threadIdx.x;
    if (i < n) { deg[i] = 1; cursor[i] = 0; }   // deg starts at 1 (self-loop)
}

__global__ __launch_bounds__(256) void k_count(const int* __restrict__ col, int* __restrict__ deg, int E) {
    int e = blockIdx.x * 256 + threadIdx.x;
    if (e < E) atomicAdd(&deg[col[e]], 1);
}

__global__ __launch_bounds__(256) void k_dinv(const int* __restrict__ deg, float* __restrict__ dinv, int n) {
    int i = blockIdx.x * 256 + threadIdx.x;
    if (i < n) dinv[i] = rsqrtf((float)deg[i]);
}

// ---------- exclusive scan of per-node edge counts (deg-1) -> row_ptr ----------
__global__ __launch_bounds__(1024) void k_scan1(const int* __restrict__ deg, int* __restrict__ ptr,
                                                int* __restrict__ bsum, int n) {
    __shared__ int s[SCAN_BLK];
    int t = threadIdx.x;
    int i = blockIdx.x * SCAN_BLK + t;
    int v = (i < n) ? (deg[i] - 1) : 0;   // real in-edges only (self-loop handled separately)
    s[t] = v;
    __syncthreads();
    for (int off = 1; off < SCAN_BLK; off <<= 1) {
        int add = (t >= off) ? s[t - off] : 0;
        __syncthreads();
        s[t] += add;
        __syncthreads();
    }
    if (i < n) ptr[i] = s[t] - v;            // exclusive
    if (t == SCAN_BLK - 1) bsum[blockIdx.x] = s[t];
}

__global__ __launch_bounds__(64) void k_scan2(int* __restrict__ bsum, int nb) {
    __shared__ int s[64];
    int t = threadIdx.x;
    int v = (t < nb) ? bsum[t] : 0;
    s[t] = v;
    __syncthreads();
    for (int off = 1; off < 64; off <<= 1) {
        int add = (t >= off) ? s[t - off] : 0;
        __syncthreads();
        s[t] += add;
        __syncthreads();
    }
    if (t < nb) bsum[t] = s[t] - v;          // exclusive block offsets
}

__global__ __launch_bounds__(256) void k_scan3(int* __restrict__ ptr, const int* __restrict__ bsum,
                                               int n, int E) {
    int i = blockIdx.x * 256 + threadIdx.x;
    if (i < n) ptr[i] += bsum[i / SCAN_BLK];
    if (i == 0) ptr[n] = E;
}

// ---------- CSR fill (bucket edges by target/col) ----------
__global__ __launch_bounds__(256) void k_fill(const int* __restrict__ row, const int* __restrict__ col,
                                              const int* __restrict__ ptr, int* __restrict__ cursor,
                                              int* __restrict__ csr_row, int E) {
    int e = blockIdx.x * 256 + threadIdx.x;
    if (e < E) {
        int c = col[e];
        int p = ptr[c] + atomicAdd(&cursor[c], 1);
        csr_row[p] = row[e];
    }
}

// ---------- aggregation in 128-dim: agg[c] = dinv[c]^2*x[c] + sum_e dinv[r]*dinv[c]*x[r] ----------
__global__ __launch_bounds__(128) void k_agg(const float* __restrict__ x, const float* __restrict__ dinv,
                                             const int* __restrict__ ptr, const int* __restrict__ csr_row,
                                             float* __restrict__ agg, int n) {
    int c = blockIdx.x;
    int t = threadIdx.x;
    float dc = dinv[c];
    float acc = x[(size_t)c * IN_C + t] * dc * dc;   // self-loop
    int e = ptr[c], end = ptr[c + 1];
    for (; e < end; ++e) {
        int r = csr_row[e];
        acc += x[(size_t)r * IN_C + t] * (dinv[r] * dc);
    }
    agg[(size_t)c * IN_C + t] = acc;
}

// ---------- fused dual-GEMV + LayerNorm + ReLU + residual ----------
__global__ __launch_bounds__(256) void k_fused(const float* __restrict__ x, const float* __restrict__ agg,
                                               const float* __restrict__ Wg, const float* __restrict__ bg,
                                               const float* __restrict__ gamma, const float* __restrict__ beta,
                                               const float* __restrict__ Wr, const float* __restrict__ br,
                                               float* __restrict__ out, int n) {
    __shared__ float xs[MTILE][IN_C];
    __shared__ float as[MTILE][IN_C];
    __shared__ float p1[4], p2[4];
    int j = threadIdx.x;                  // output column 0..255
    int node0 = blockIdx.x * MTILE;

    for (int i = j; i < MTILE * IN_C; i += 256) {
        int m = i >> 7, k = i & (IN_C - 1);
        int nd = node0 + m;
        if (nd < n) {
            xs[m][k] = x[(size_t)nd * IN_C + k];
            as[m][k] = agg[(size_t)nd * IN_C + k];
        } else {
            xs[m][k] = 0.f;
            as[m][k] = 0.f;
        }
    }
    __syncthreads();

    float accg[MTILE], accr[MTILE];
#pragma unroll
    for (int m = 0; m < MTILE; ++m) { accg[m] = 0.f; accr[m] = 0.f; }

    const float4* xs4 = reinterpret_cast<const float4*>(&xs[0][0]);
    const float4* as4 = reinterpret_cast<const float4*>(&as[0][0]);

    for (int k4 = 0; k4 < IN_C / 4; ++k4) {
        int k = k4 * 4;
        float wg0 = Wg[(k + 0) * OUT_C + j];
        float wg1 = Wg[(k + 1) * OUT_C + j];
        float wg2 = Wg[(k + 2) * OUT_C + j];
        float wg3 = Wg[(k + 3) * OUT_C + j];
        float wr0 = Wr[(k + 0) * OUT_C + j];
        float wr1 = Wr[(k + 1) * OUT_C + j];
        float wr2 = Wr[(k + 2) * OUT_C + j];
        float wr3 = Wr[(k + 3) * OUT_C + j];
#pragma unroll
        for (int m = 0; m < MTILE; ++m) {
            float4 a  = as4[m * (IN_C / 4) + k4];
            float4 xv = xs4[m * (IN_C / 4) + k4];
            accg[m] += a.x * wg0;  accg[m] += a.y * wg1;
            accg[m] += a.z * wg2;  accg[m] += a.w * wg3;
            accr[m] += xv.x * wr0; accr[m] += xv.y * wr1;
            accr[m] += xv.z * wr2; accr[m] += xv.w * wr3;
        }
    }

    float bgj = bg[j], brj = br[j], gj = gamma[j], bj = beta[j];
    int lane = j & 63, wave = j >> 6;

    for (int m = 0; m < MTILE; ++m) {
        float v = accg[m] + bgj;
        float s1 = v, s2 = v * v;
#pragma unroll
        for (int off = 32; off; off >>= 1) {
            s1 += __shfl_down(s1, off);
            s2 += __shfl_down(s2, off);
        }
        if (lane == 0) { p1[wave] = s1; p2[wave] = s2; }
        __syncthreads();
        float sum1 = p1[0] + p1[1] + p1[2] + p1[3];
        float sum2 = p2[0] + p2[1] + p2[2] + p2[3];
        float mu  = sum1 * (1.f / OUT_C);
        float var = sum2 * (1.f / OUT_C) - mu * mu;
        float rs  = rsqrtf(var + LN_EPS);
        float ln  = (v - mu) * rs * gj + bj;
        float r   = fmaxf(ln, 0.f) + accr[m] + brj;
        int nd = node0 + m;
        if (nd < n) out[(size_t)nd * OUT_C + j] = r;
        __syncthreads();   // protect p1/p2 before next iteration
    }
}

extern "C" void kernel_launch(void* const* d_in, const int* in_sizes, int n_in,
                              void* d_out, int out_size, void* d_ws, size_t ws_size,
                              hipStream_t stream) {
    const float* x     = (const float*)d_in[0];
    const int*   ei    = (const int*)d_in[1];
    const float* Wg    = (const float*)d_in[2];
    const float* bg    = (const float*)d_in[3];
    const float* gamma = (const float*)d_in[4];
    const float* beta  = (const float*)d_in[5];
    const float* Wr    = (const float*)d_in[6];
    const float* br    = (const float*)d_in[7];
    float* out = (float*)d_out;

    int N = in_sizes[0] / IN_C;
    int E = in_sizes[1] / 2;
    const int* row = ei;
    const int* col = ei + E;

    // workspace carve-out (~30 MB)
    char* ws = (char*)d_ws;
    size_t off = 0;
    auto alloc = [&](size_t bytes) -> void* {
        void* p = ws + off;
        off += (bytes + 255) & ~(size_t)255;
        return p;
    };
    float* agg     = (float*)alloc((size_t)N * IN_C * sizeof(float));
    float* dinv    = (float*)alloc((size_t)N * sizeof(float));
    int*   deg     = (int*)alloc((size_t)N * sizeof(int));
    int*   ptr     = (int*)alloc((size_t)(N + 1) * sizeof(int));
    int*   cursor  = (int*)alloc((size_t)N * sizeof(int));
    int*   bsum    = (int*)alloc(64 * sizeof(int));
    int*   csr_row = (int*)alloc((size_t)E * sizeof(int));
    (void)ws_size; (void)n_in; (void)out_size;

    int nbN = (N + 255) / 256;
    int nbE = (E + 255) / 256;
    int nsb = (N + SCAN_BLK - 1) / SCAN_BLK;   // 49 <= 64

    k_init <<<nbN, 256, 0, stream>>>(deg, cursor, N);
    k_count<<<nbE, 256, 0, stream>>>(col, deg, E);
    k_dinv <<<nbN, 256, 0, stream>>>(deg, dinv, N);
    k_scan1<<<nsb, 1024, 0, stream>>>(deg, ptr, bsum, N);
    k_scan2<<<1, 64, 0, stream>>>(bsum, nsb);
    k_scan3<<<nbN, 256, 0, stream>>>(ptr, bsum, N, E);
    k_fill <<<nbE, 256, 0, stream>>>(row, col, ptr, cursor, csr_row, E);
    k_agg  <<<N, 128, 0, stream>>>(x, dinv, ptr, csr_row, agg, N);
    k_fused<<<(N + MTILE - 1) / MTILE, 256, 0, stream>>>(x, agg, Wg, bg, gamma, beta, Wr, br, out, N);
}

// Round 2
// 224.585 us; speedup vs baseline: 1.5777x; 1.5777x over previous
//
#include <hip/hip_runtime.h>

#define IN_C 128
#define OUT_C 256
#define LN_EPS 1e-5f
#define SCAN_BLK 1024

typedef __attribute__((ext_vector_type(8))) short bf16x8;
typedef __attribute__((ext_vector_type(4))) float f32x4;

__device__ __forceinline__ unsigned int f2bf(float f) {
    unsigned int u = __float_as_uint(f);
    return (u + 0x7fffu + ((u >> 16) & 1u)) >> 16;   // RNE
}
__device__ __forceinline__ float bf_lo(unsigned int p) { return __uint_as_float(p << 16); }
__device__ __forceinline__ float bf_hi(unsigned int p) { return __uint_as_float(p & 0xffff0000u); }

// ---------- setup: deg/cursor init + x->bf16 + weight->fragment-order bf16 ----------
__global__ __launch_bounds__(256) void k_setup(const float* __restrict__ x,
                                               const float* __restrict__ Wg,
                                               const float* __restrict__ Wr,
                                               unsigned short* __restrict__ x_bf,
                                               unsigned short* __restrict__ wgf,
                                               unsigned short* __restrict__ wrf,
                                               int* __restrict__ deg, int* __restrict__ cursor,
                                               int n) {
    int gid = blockIdx.x * 256 + threadIdx.x;
    int nx8 = n * (IN_C / 8);
    if (gid < nx8) {   // convert 8 floats -> 8 bf16 (16B store)
        const float4* xv = reinterpret_cast<const float4*>(x) + (size_t)gid * 2;
        float4 a = xv[0], b = xv[1];
        uint4 o;
        o.x = f2bf(a.x) | (f2bf(a.y) << 16);
        o.y = f2bf(a.z) | (f2bf(a.w) << 16);
        o.z = f2bf(b.x) | (f2bf(b.y) << 16);
        o.w = f2bf(b.z) | (f2bf(b.w) << 16);
        reinterpret_cast<uint4*>(x_bf)[gid] = o;
    }
    if (gid < n) { deg[gid] = 1; cursor[gid] = 0; }
    if (gid < 8192) {  // weight fragments: one thread = one (weight, ct, kt, lane) -> 8 bf16
        int wsel = gid >> 12;
        int u = gid & 4095;
        int ct = u >> 8, kt = (u >> 6) & 3, l = u & 63;
        int k0 = kt * 32 + (l >> 4) * 8;
        int col = ct * 16 + (l & 15);
        const float* W = wsel ? Wr : Wg;
        unsigned short* Wf = wsel ? wrf : wgf;
        uint4 o;
        unsigned int s[8];
#pragma unroll
        for (int e = 0; e < 8; ++e) s[e] = f2bf(W[(size_t)(k0 + e) * OUT_C + col]);
        o.x = s[0] | (s[1] << 16); o.y = s[2] | (s[3] << 16);
        o.z = s[4] | (s[5] << 16); o.w = s[6] | (s[7] << 16);
        reinterpret_cast<uint4*>(Wf)[u] = o;
    }
}

// ---------- degree count (4 edges/thread) ----------
__global__ __launch_bounds__(256) void k_count(const int* __restrict__ col, int* __restrict__ deg, int E) {
    int i = blockIdx.x * 256 + threadIdx.x;
    int base = i * 4;
    if (base + 3 < E) {
        int4 c = *reinterpret_cast<const int4*>(col + base);
        atomicAdd(&deg[c.x], 1); atomicAdd(&deg[c.y], 1);
        atomicAdd(&deg[c.z], 1); atomicAdd(&deg[c.w], 1);
    } else {
        for (int e = base; e < E; ++e) atomicAdd(&deg[col[e]], 1);
    }
}

// ---------- scan of (deg-1) -> exclusive ptr, plus dinv ----------
__global__ __launch_bounds__(1024) void k_scan1(const int* __restrict__ deg, int* __restrict__ ptr,
                                                int* __restrict__ bsum, float* __restrict__ dinv, int n) {
    __shared__ int s[SCAN_BLK];
    int t = threadIdx.x;
    int i = blockIdx.x * SCAN_BLK + t;
    int v = (i < n) ? (deg[i] - 1) : 0;
    s[t] = v;
    __syncthreads();
    for (int off = 1; off < SCAN_BLK; off <<= 1) {
        int add = (t >= off) ? s[t - off] : 0;
        __syncthreads();
        s[t] += add;
        __syncthreads();
    }
    if (i < n) { ptr[i] = s[t] - v; dinv[i] = rsqrtf((float)(v + 1)); }
    if (t == SCAN_BLK - 1) bsum[blockIdx.x] = s[t];
}

__global__ __launch_bounds__(64) void k_scan2(int* __restrict__ bsum, int nb) {
    __shared__ int s[64];
    int t = threadIdx.x;
    int v = (t < nb) ? bsum[t] : 0;
    s[t] = v;
    __syncthreads();
    for (int off = 1; off < 64; off <<= 1) {
        int add = (t >= off) ? s[t - off] : 0;
        __syncthreads();
        s[t] += add;
        __syncthreads();
    }
    if (t < nb) bsum[t] = s[t] - v;
}

__global__ __launch_bounds__(256) void k_scan3(int* __restrict__ ptr, const int* __restrict__ bsum,
                                               int n, int E) {
    int i = blockIdx.x * 256 + threadIdx.x;
    if (i < n) ptr[i] += bsum[i / SCAN_BLK];
    if (i == 0) ptr[n] = E;
}

// ---------- CSR fill (4 edges/thread) ----------
__global__ __launch_bounds__(256) void k_fill(const int* __restrict__ row, const int* __restrict__ col,
                                              const int* __restrict__ ptr, int* __restrict__ cursor,
                                              int* __restrict__ csr_row, int E) {
    int i = blockIdx.x * 256 + threadIdx.x;
    int base = i * 4;
    if (base + 3 < E) {
        int4 r = *reinterpret_cast<const int4*>(row + base);
        int4 c = *reinterpret_cast<const int4*>(col + base);
        csr_row[ptr[c.x] + atomicAdd(&cursor[c.x], 1)] = r.x;
        csr_row[ptr[c.y] + atomicAdd(&cursor[c.y], 1)] = r.y;
        csr_row[ptr[c.z] + atomicAdd(&cursor[c.z], 1)] = r.z;
        csr_row[ptr[c.w] + atomicAdd(&cursor[c.w], 1)] = r.w;
    } else {
        for (int e = base; e < E; ++e) {
            int c = col[e];
            csr_row[ptr[c] + atomicAdd(&cursor[c], 1)] = row[e];
        }
    }
}

// ---------- bf16 aggregation: one wave per node, 2 cols/lane ----------
__global__ __launch_bounds__(256) void k_agg(const unsigned short* __restrict__ x_bf,
                                             const float* __restrict__ dinv,
                                             const int* __restrict__ ptr,
                                             const int* __restrict__ csr_row,
                                             unsigned short* __restrict__ agg_bf, int n) {
    int c = blockIdx.x * 4 + (threadIdx.x >> 6);
    if (c >= n) return;
    int lane = threadIdx.x & 63;
    float dc = dinv[c];
    unsigned int p = *reinterpret_cast<const unsigned int*>(x_bf + (size_t)c * IN_C + lane * 2);
    float a0 = bf_lo(p) * dc * dc;
    float a1 = bf_hi(p) * dc * dc;
    int e = ptr[c], end = ptr[c + 1];
    for (; e < end; ++e) {
        int r = csr_row[e];
        float w = dinv[r] * dc;
        unsigned int q = *reinterpret_cast<const unsigned int*>(x_bf + (size_t)r * IN_C + lane * 2);
        a0 += bf_lo(q) * w;
        a1 += bf_hi(q) * w;
    }
    unsigned int o = f2bf(a0) | (f2bf(a1) << 16);
    *reinterpret_cast<unsigned int*>(agg_bf + (size_t)c * IN_C + lane * 2) = o;
}

// ---------- fused MFMA dual-GEMM + LayerNorm + ReLU + residual ----------
__global__ __launch_bounds__(256) void k_mfma(const unsigned short* __restrict__ agg_bf,
                                              const unsigned short* __restrict__ x_bf,
                                              const unsigned short* __restrict__ wgf,
                                              const unsigned short* __restrict__ wrf,
                                              const float* __restrict__ bgc,
                                              const float* __restrict__ gamma,
                                              const float* __restrict__ beta,
                                              const float* __restrict__ brc,
                                              float* __restrict__ out, int n) {
    int tid = threadIdx.x;
    int w = tid >> 6, l = tid & 63;
    int row0 = blockIdx.x * 32;
    int rtile = w & 1;               // which 16-row tile
    int colhalf = (w >> 1) * 128;    // which 128-col half
    int g = l >> 4;                  // k-group / row-group

    // A fragments (agg and x), clamped for tail rows
    int mrow = row0 + rtile * 16 + (l & 15);
    if (mrow >= n) mrow = n - 1;
    bf16x8 aagg[4], ax[4];
#pragma unroll
    for (int kt = 0; kt < 4; ++kt) {
        aagg[kt] = *reinterpret_cast<const bf16x8*>(agg_bf + (size_t)mrow * IN_C + kt * 32 + g * 8);
        ax[kt]   = *reinterpret_cast<const bf16x8*>(x_bf   + (size_t)mrow * IN_C + kt * 32 + g * 8);
    }

    f32x4 accg[8], accr[8];
#pragma unroll
    for (int ct = 0; ct < 8; ++ct) {
        accg[ct] = (f32x4){0.f, 0.f, 0.f, 0.f};
        accr[ct] = (f32x4){0.f, 0.f, 0.f, 0.f};
    }

#pragma unroll
    for (int ct = 0; ct < 8; ++ct) {
        int cg = (w >> 1) * 8 + ct;
#pragma unroll
        for (int kt = 0; kt < 4; ++kt) {
            bf16x8 bg_ = *reinterpret_cast<const bf16x8*>(wgf + ((size_t)(cg * 4 + kt) * 64 + l) * 8);
            bf16x8 br_ = *reinterpret_cast<const bf16x8*>(wrf + ((size_t)(cg * 4 + kt) * 64 + l) * 8);
            accg[ct] = __builtin_amdgcn_mfma_f32_16x16x32_bf16(aagg[kt], bg_, accg[ct], 0, 0, 0);
            accr[ct] = __builtin_amdgcn_mfma_f32_16x16x32_bf16(ax[kt],   br_, accr[ct], 0, 0, 0);
        }
    }

    // ---- LayerNorm over 256 cols: add b_gcn, partial sums, 16-lane butterfly ----
    float s1[4] = {0.f, 0.f, 0.f, 0.f}, s2[4] = {0.f, 0.f, 0.f, 0.f};
#pragma unroll
    for (int ct = 0; ct < 8; ++ct) {
        int col = colhalf + ct * 16 + (l & 15);
        float b = bgc[col];
#pragma unroll
        for (int r = 0; r < 4; ++r) {
            float v = accg[ct][r] + b;
            accg[ct][r] = v;
            s1[r] += v;
            s2[r] += v * v;
        }
    }
#pragma unroll
    for (int off = 1; off < 16; off <<= 1) {
#pragma unroll
        for (int r = 0; r < 4; ++r) {
            s1[r] += __shfl_xor(s1[r], off);
            s2[r] += __shfl_xor(s2[r], off);
        }
    }

    // cross-wave combine (waves w and w^2 share rows, different col halves)
    __shared__ float red1[4][16], red2[4][16];
    if ((l & 15) == 0) {
#pragma unroll
        for (int r = 0; r < 4; ++r) {
            red1[w][g * 4 + r] = s1[r];
            red2[w][g * 4 + r] = s2[r];
        }
    }
    __syncthreads();
    int wp = w ^ 2;
    float mu[4], rs[4];
#pragma unroll
    for (int r = 0; r < 4; ++r) {
        float t1 = s1[r] + red1[wp][g * 4 + r];
        float t2 = s2[r] + red2[wp][g * 4 + r];
        float m = t1 * (1.f / OUT_C);
        float var = t2 * (1.f / OUT_C) - m * m;
        mu[r] = m;
        rs[r] = rsqrtf(var + LN_EPS);
    }

    // ---- epilogue: LN * gamma + beta, ReLU, + residual, store ----
#pragma unroll
    for (int ct = 0; ct < 8; ++ct) {
        int col = colhalf + ct * 16 + (l & 15);
        float ga = gamma[col], be = beta[col], brv = brc[col];
#pragma unroll
        for (int r = 0; r < 4; ++r) {
            int rown = row0 + rtile * 16 + g * 4 + r;
            if (rown < n) {
                float ln = (accg[ct][r] - mu[r]) * rs[r] * ga + be;
                float val = fmaxf(ln, 0.f) + accr[ct][r] + brv;
                out[(size_t)rown * OUT_C + col] = val;
            }
        }
    }
}

extern "C" void kernel_launch(void* const* d_in, const int* in_sizes, int n_in,
                              void* d_out, int out_size, void* d_ws, size_t ws_size,
                              hipStream_t stream) {
    const float* x     = (const float*)d_in[0];
    const int*   ei    = (const int*)d_in[1];
    const float* Wg    = (const float*)d_in[2];
    const float* bg    = (const float*)d_in[3];
    const float* gamma = (const float*)d_in[4];
    const float* beta  = (const float*)d_in[5];
    const float* Wr    = (const float*)d_in[6];
    const float* br    = (const float*)d_in[7];
    float* out = (float*)d_out;

    int N = in_sizes[0] / IN_C;
    int E = in_sizes[1] / 2;
    const int* row = ei;
    const int* col = ei + E;

    char* ws = (char*)d_ws;
    size_t off = 0;
    auto alloc = [&](size_t bytes) -> void* {
        void* p = ws + off;
        off += (bytes + 255) & ~(size_t)255;
        return p;
    };
    unsigned short* x_bf   = (unsigned short*)alloc((size_t)N * IN_C * 2);
    unsigned short* agg_bf = (unsigned short*)alloc((size_t)N * IN_C * 2);
    unsigned short* wgf    = (unsigned short*)alloc((size_t)IN_C * OUT_C * 2);
    unsigned short* wrf    = (unsigned short*)alloc((size_t)IN_C * OUT_C * 2);
    float* dinv    = (float*)alloc((size_t)N * sizeof(float));
    int*   deg     = (int*)alloc((size_t)N * sizeof(int));
    int*   ptr     = (int*)alloc((size_t)(N + 1) * sizeof(int));
    int*   cursor  = (int*)alloc((size_t)N * sizeof(int));
    int*   bsum    = (int*)alloc(64 * sizeof(int));
    int*   csr_row = (int*)alloc((size_t)E * sizeof(int));
    (void)ws_size; (void)n_in; (void)out_size;

    int nbN  = (N + 255) / 256;
    int nbE4 = (E + 1023) / 1024;
    int nsb  = (N + SCAN_BLK - 1) / SCAN_BLK;
    int nsetup = (N * (IN_C / 8) + 255) / 256;

    k_setup<<<nsetup, 256, 0, stream>>>(x, Wg, Wr, x_bf, wgf, wrf, deg, cursor, N);
    k_count<<<nbE4, 256, 0, stream>>>(col, deg, E);
    k_scan1<<<nsb, 1024, 0, stream>>>(deg, ptr, bsum, dinv, N);
    k_scan2<<<1, 64, 0, stream>>>(bsum, nsb);
    k_scan3<<<nbN, 256, 0, stream>>>(ptr, bsum, N, E);
    k_fill <<<nbE4, 256, 0, stream>>>(row, col, ptr, cursor, csr_row, E);
    k_agg  <<<(N + 3) / 4, 256, 0, stream>>>(x_bf, dinv, ptr, csr_row, agg_bf, N);
    k_mfma <<<(N + 31) / 32, 256, 0, stream>>>(agg_bf, x_bf, wgf, wrf, bg, gamma, beta, br, out, N);
}

// Round 3
// 189.872 us; speedup vs baseline: 1.8661x; 1.1828x over previous
//
#include <hip/hip_runtime.h>

#define IN_C 128
#define OUT_C 256
#define LN_EPS 1e-5f
#define SCAN_BLK 1024

typedef __attribute__((ext_vector_type(8))) short bf16x8;
typedef __attribute__((ext_vector_type(4))) float f32x4;

__device__ __forceinline__ unsigned int f2bf(float f) {
    unsigned int u = __float_as_uint(f);
    return (u + 0x7fffu + ((u >> 16) & 1u)) >> 16;   // RNE
}
__device__ __forceinline__ float bf_lo(unsigned int p) { return __uint_as_float(p << 16); }
__device__ __forceinline__ float bf_hi(unsigned int p) { return __uint_as_float(p & 0xffff0000u); }

// ---------- degree count (4 edges/thread); deg pre-zeroed by memset ----------
__global__ __launch_bounds__(256) void k_count(const int* __restrict__ col, int* __restrict__ deg, int E) {
    int i = blockIdx.x * 256 + threadIdx.x;
    int base = i * 4;
    if (base + 3 < E) {
        int4 c = *reinterpret_cast<const int4*>(col + base);
        atomicAdd(&deg[c.x], 1); atomicAdd(&deg[c.y], 1);
        atomicAdd(&deg[c.z], 1); atomicAdd(&deg[c.w], 1);
    } else {
        for (int e = base; e < E; ++e) atomicAdd(&deg[col[e]], 1);
    }
}

// ---------- scan of deg (in-edge counts) -> exclusive ptr, plus dinv = rsqrt(deg+1) ----------
__global__ __launch_bounds__(1024) void k_scan1(const int* __restrict__ deg, int* __restrict__ ptr,
                                                int* __restrict__ bsum, float* __restrict__ dinv, int n) {
    __shared__ int s[SCAN_BLK];
    int t = threadIdx.x;
    int i = blockIdx.x * SCAN_BLK + t;
    int v = (i < n) ? deg[i] : 0;
    s[t] = v;
    __syncthreads();
    for (int off = 1; off < SCAN_BLK; off <<= 1) {
        int add = (t >= off) ? s[t - off] : 0;
        __syncthreads();
        s[t] += add;
        __syncthreads();
    }
    if (i < n) { ptr[i] = s[t] - v; dinv[i] = rsqrtf((float)(v + 1)); }
    if (t == SCAN_BLK - 1) bsum[blockIdx.x] = s[t];
}

__global__ __launch_bounds__(64) void k_scan2(int* __restrict__ bsum, int nb) {
    __shared__ int s[64];
    int t = threadIdx.x;
    int v = (t < nb) ? bsum[t] : 0;
    s[t] = v;
    __syncthreads();
    for (int off = 1; off < 64; off <<= 1) {
        int add = (t >= off) ? s[t - off] : 0;
        __syncthreads();
        s[t] += add;
        __syncthreads();
    }
    if (t < nb) bsum[t] = s[t] - v;
}

__global__ __launch_bounds__(256) void k_scan3(int* __restrict__ ptr, const int* __restrict__ bsum,
                                               int n, int E) {
    int i = blockIdx.x * 256 + threadIdx.x;
    if (i < n) ptr[i] += bsum[i / SCAN_BLK];
    if (i == 0) ptr[n] = E;
}

// ---------- conversions: x->bf16 (plain and dinv-scaled), weights->fragment order ----------
__global__ __launch_bounds__(256) void k_convert(const float* __restrict__ x,
                                                 const float* __restrict__ dinv,
                                                 const float* __restrict__ Wg,
                                                 const float* __restrict__ Wr,
                                                 unsigned short* __restrict__ x_bf,
                                                 unsigned short* __restrict__ xs_bf,
                                                 unsigned short* __restrict__ wgf,
                                                 unsigned short* __restrict__ wrf,
                                                 int n) {
    int gid = blockIdx.x * 256 + threadIdx.x;
    int nx8 = n * (IN_C / 8);
    if (gid < nx8) {
        float dn = dinv[gid >> 4];
        const float4* xv = reinterpret_cast<const float4*>(x) + (size_t)gid * 2;
        float4 a = xv[0], b = xv[1];
        uint4 o, os;
        o.x  = f2bf(a.x) | (f2bf(a.y) << 16);
        o.y  = f2bf(a.z) | (f2bf(a.w) << 16);
        o.z  = f2bf(b.x) | (f2bf(b.y) << 16);
        o.w  = f2bf(b.z) | (f2bf(b.w) << 16);
        os.x = f2bf(a.x * dn) | (f2bf(a.y * dn) << 16);
        os.y = f2bf(a.z * dn) | (f2bf(a.w * dn) << 16);
        os.z = f2bf(b.x * dn) | (f2bf(b.y * dn) << 16);
        os.w = f2bf(b.z * dn) | (f2bf(b.w * dn) << 16);
        reinterpret_cast<uint4*>(x_bf)[gid]  = o;
        reinterpret_cast<uint4*>(xs_bf)[gid] = os;
    }
    if (gid < 8192) {  // weight fragments: one thread = one (weight, ct, kt, lane) -> 8 bf16
        int wsel = gid >> 12;
        int u = gid & 4095;
        int ct = u >> 8, kt = (u >> 6) & 3, l = u & 63;
        int k0 = kt * 32 + (l >> 4) * 8;
        int colw = ct * 16 + (l & 15);
        const float* W = wsel ? Wr : Wg;
        unsigned short* Wf = wsel ? wrf : wgf;
        uint4 o;
        unsigned int s[8];
#pragma unroll
        for (int e = 0; e < 8; ++e) s[e] = f2bf(W[(size_t)(k0 + e) * OUT_C + colw]);
        o.x = s[0] | (s[1] << 16); o.y = s[2] | (s[3] << 16);
        o.z = s[4] | (s[5] << 16); o.w = s[6] | (s[7] << 16);
        reinterpret_cast<uint4*>(Wf)[u] = o;
    }
}

// ---------- CSR fill (4 edges/thread) ----------
__global__ __launch_bounds__(256) void k_fill(const int* __restrict__ row, const int* __restrict__ col,
                                              const int* __restrict__ ptr, int* __restrict__ cursor,
                                              int* __restrict__ csr_row, int E) {
    int i = blockIdx.x * 256 + threadIdx.x;
    int base = i * 4;
    if (base + 3 < E) {
        int4 r = *reinterpret_cast<const int4*>(row + base);
        int4 c = *reinterpret_cast<const int4*>(col + base);
        csr_row[ptr[c.x] + atomicAdd(&cursor[c.x], 1)] = r.x;
        csr_row[ptr[c.y] + atomicAdd(&cursor[c.y], 1)] = r.y;
        csr_row[ptr[c.z] + atomicAdd(&cursor[c.z], 1)] = r.z;
        csr_row[ptr[c.w] + atomicAdd(&cursor[c.w], 1)] = r.w;
    } else {
        for (int e = base; e < E; ++e) {
            int c = col[e];
            csr_row[ptr[c] + atomicAdd(&cursor[c], 1)] = row[e];
        }
    }
}

// ---------- aggregation: agg[c] = dinv[c] * (xs[c] + sum_e xs[r]), xs pre-scaled ----------
// one wave per node, 2 bf16 cols/lane, edge loop unrolled x4 for MLP
__global__ __launch_bounds__(256) void k_agg(const unsigned int* __restrict__ xs32,
                                             const float* __restrict__ dinv,
                                             const int* __restrict__ ptr,
                                             const int* __restrict__ csr_row,
                                             unsigned short* __restrict__ agg_bf, int n) {
    int c = blockIdx.x * 4 + (threadIdx.x >> 6);
    if (c >= n) return;
    int lane = threadIdx.x & 63;
    float dc = dinv[c];
    unsigned int p = xs32[(size_t)c * 64 + lane];
    float a0 = bf_lo(p), a1 = bf_hi(p);
    int e = ptr[c], end = ptr[c + 1];
    for (; e + 4 <= end; e += 4) {
        int r0 = csr_row[e], r1 = csr_row[e + 1], r2 = csr_row[e + 2], r3 = csr_row[e + 3];
        unsigned int q0 = xs32[(size_t)r0 * 64 + lane];
        unsigned int q1 = xs32[(size_t)r1 * 64 + lane];
        unsigned int q2 = xs32[(size_t)r2 * 64 + lane];
        unsigned int q3 = xs32[(size_t)r3 * 64 + lane];
        a0 += bf_lo(q0); a1 += bf_hi(q0);
        a0 += bf_lo(q1); a1 += bf_hi(q1);
        a0 += bf_lo(q2); a1 += bf_hi(q2);
        a0 += bf_lo(q3); a1 += bf_hi(q3);
    }
    for (; e < end; ++e) {
        unsigned int q = xs32[(size_t)csr_row[e] * 64 + lane];
        a0 += bf_lo(q); a1 += bf_hi(q);
    }
    a0 *= dc; a1 *= dc;
    *reinterpret_cast<unsigned int*>(agg_bf + (size_t)c * IN_C + lane * 2) = f2bf(a0) | (f2bf(a1) << 16);
}

// ---------- fused MFMA dual-GEMM + LayerNorm + ReLU + residual ----------
__global__ __launch_bounds__(256) void k_mfma(const unsigned short* __restrict__ agg_bf,
                                              const unsigned short* __restrict__ x_bf,
                                              const unsigned short* __restrict__ wgf,
                                              const unsigned short* __restrict__ wrf,
                                              const float* __restrict__ bgc,
                                              const float* __restrict__ gamma,
                                              const float* __restrict__ beta,
                                              const float* __restrict__ brc,
                                              float* __restrict__ out, int n) {
    int tid = threadIdx.x;
    int w = tid >> 6, l = tid & 63;
    int row0 = blockIdx.x * 32;
    int rtile = w & 1;               // which 16-row tile
    int colhalf = (w >> 1) * 128;    // which 128-col half
    int g = l >> 4;                  // k-group / row-group

    int mrow = row0 + rtile * 16 + (l & 15);
    if (mrow >= n) mrow = n - 1;
    bf16x8 aagg[4], ax[4];
#pragma unroll
    for (int kt = 0; kt < 4; ++kt) {
        aagg[kt] = *reinterpret_cast<const bf16x8*>(agg_bf + (size_t)mrow * IN_C + kt * 32 + g * 8);
        ax[kt]   = *reinterpret_cast<const bf16x8*>(x_bf   + (size_t)mrow * IN_C + kt * 32 + g * 8);
    }

    f32x4 accg[8], accr[8];
#pragma unroll
    for (int ct = 0; ct < 8; ++ct) {
        accg[ct] = (f32x4){0.f, 0.f, 0.f, 0.f};
        accr[ct] = (f32x4){0.f, 0.f, 0.f, 0.f};
    }

#pragma unroll
    for (int ct = 0; ct < 8; ++ct) {
        int cg = (w >> 1) * 8 + ct;
#pragma unroll
        for (int kt = 0; kt < 4; ++kt) {
            bf16x8 bg_ = *reinterpret_cast<const bf16x8*>(wgf + ((size_t)(cg * 4 + kt) * 64 + l) * 8);
            bf16x8 br_ = *reinterpret_cast<const bf16x8*>(wrf + ((size_t)(cg * 4 + kt) * 64 + l) * 8);
            accg[ct] = __builtin_amdgcn_mfma_f32_16x16x32_bf16(aagg[kt], bg_, accg[ct], 0, 0, 0);
            accr[ct] = __builtin_amdgcn_mfma_f32_16x16x32_bf16(ax[kt],   br_, accr[ct], 0, 0, 0);
        }
    }

    // ---- LayerNorm partial sums ----
    float s1[4] = {0.f, 0.f, 0.f, 0.f}, s2[4] = {0.f, 0.f, 0.f, 0.f};
#pragma unroll
    for (int ct = 0; ct < 8; ++ct) {
        int colj = colhalf + ct * 16 + (l & 15);
        float b = bgc[colj];
#pragma unroll
        for (int r = 0; r < 4; ++r) {
            float v = accg[ct][r] + b;
            accg[ct][r] = v;
            s1[r] += v;
            s2[r] += v * v;
        }
    }
#pragma unroll
    for (int off = 1; off < 16; off <<= 1) {
#pragma unroll
        for (int r = 0; r < 4; ++r) {
            s1[r] += __shfl_xor(s1[r], off);
            s2[r] += __shfl_xor(s2[r], off);
        }
    }

    __shared__ float red1[4][16], red2[4][16];
    if ((l & 15) == 0) {
#pragma unroll
        for (int r = 0; r < 4; ++r) {
            red1[w][g * 4 + r] = s1[r];
            red2[w][g * 4 + r] = s2[r];
        }
    }
    __syncthreads();
    int wp = w ^ 2;
    float mu[4], rs[4];
#pragma unroll
    for (int r = 0; r < 4; ++r) {
        float t1 = s1[r] + red1[wp][g * 4 + r];
        float t2 = s2[r] + red2[wp][g * 4 + r];
        float m = t1 * (1.f / OUT_C);
        float var = t2 * (1.f / OUT_C) - m * m;
        mu[r] = m;
        rs[r] = rsqrtf(var + LN_EPS);
    }

#pragma unroll
    for (int ct = 0; ct < 8; ++ct) {
        int colj = colhalf + ct * 16 + (l & 15);
        float ga = gamma[colj], be = beta[colj], brv = brc[colj];
#pragma unroll
        for (int r = 0; r < 4; ++r) {
            int rown = row0 + rtile * 16 + g * 4 + r;
            if (rown < n) {
                float ln = (accg[ct][r] - mu[r]) * rs[r] * ga + be;
                float val = fmaxf(ln, 0.f) + accr[ct][r] + brv;
                out[(size_t)rown * OUT_C + colj] = val;
            }
        }
    }
}

extern "C" void kernel_launch(void* const* d_in, const int* in_sizes, int n_in,
                              void* d_out, int out_size, void* d_ws, size_t ws_size,
                              hipStream_t stream) {
    const float* x     = (const float*)d_in[0];
    const int*   ei    = (const int*)d_in[1];
    const float* Wg    = (const float*)d_in[2];
    const float* bg    = (const float*)d_in[3];
    const float* gamma = (const float*)d_in[4];
    const float* beta  = (const float*)d_in[5];
    const float* Wr    = (const float*)d_in[6];
    const float* br    = (const float*)d_in[7];
    float* out = (float*)d_out;

    int N = in_sizes[0] / IN_C;
    int E = in_sizes[1] / 2;
    const int* row = ei;
    const int* col = ei + E;

    char* ws = (char*)d_ws;
    size_t off = 0;
    auto alloc = [&](size_t bytes) -> void* {
        void* p = ws + off;
        off += (bytes + 255) & ~(size_t)255;
        return p;
    };
    unsigned short* x_bf   = (unsigned short*)alloc((size_t)N * IN_C * 2);
    unsigned short* xs_bf  = (unsigned short*)alloc((size_t)N * IN_C * 2);
    unsigned short* agg_bf = (unsigned short*)alloc((size_t)N * IN_C * 2);
    unsigned short* wgf    = (unsigned short*)alloc((size_t)IN_C * OUT_C * 2);
    unsigned short* wrf    = (unsigned short*)alloc((size_t)IN_C * OUT_C * 2);
    float* dinv    = (float*)alloc((size_t)N * sizeof(float));
    int*   deg     = (int*)alloc((size_t)N * sizeof(int));
    int*   ptr     = (int*)alloc((size_t)(N + 1) * sizeof(int));
    int*   cursor  = (int*)alloc((size_t)N * sizeof(int));
    int*   bsum    = (int*)alloc(64 * sizeof(int));
    int*   csr_row = (int*)alloc((size_t)E * sizeof(int));
    (void)ws_size; (void)n_in; (void)out_size;

    int nbN  = (N + 255) / 256;
    int nbE4 = (E + 1023) / 1024;
    int nsb  = (N + SCAN_BLK - 1) / SCAN_BLK;
    int ncvt = (N * (IN_C / 8) + 255) / 256;

    hipMemsetAsync(deg, 0, (size_t)N * sizeof(int), stream);
    hipMemsetAsync(cursor, 0, (size_t)N * sizeof(int), stream);
    k_count  <<<nbE4, 256, 0, stream>>>(col, deg, E);
    k_scan1  <<<nsb, 1024, 0, stream>>>(deg, ptr, bsum, dinv, N);
    k_scan2  <<<1, 64, 0, stream>>>(bsum, nsb);
    k_scan3  <<<nbN, 256, 0, stream>>>(ptr, bsum, N, E);
    k_fill   <<<nbE4, 256, 0, stream>>>(row, col, ptr, cursor, csr_row, E);
    k_convert<<<ncvt, 256, 0, stream>>>(x, dinv, Wg, Wr, x_bf, xs_bf, wgf, wrf, N);
    k_agg    <<<(N + 3) / 4, 256, 0, stream>>>((const unsigned int*)xs_bf, dinv, ptr, csr_row, agg_bf, N);
    k_mfma   <<<(N + 31) / 32, 256, 0, stream>>>(agg_bf, x_bf, wgf, wrf, bg, gamma, beta, br, out, N);
}

// Round 4
// 156.875 us; speedup vs baseline: 2.2587x; 1.2103x over previous
//
#include <hip/hip_runtime.h>

#define IN_C 128
#define OUT_C 256
#define LN_EPS 1e-5f
#define SCAN_BLK 1024

typedef __attribute__((ext_vector_type(8))) short bf16x8;
typedef __attribute__((ext_vector_type(4))) float f32x4;

__device__ __forceinline__ unsigned int f2bf(float f) {
    unsigned int u = __float_as_uint(f);
    return (u + 0x7fffu + ((u >> 16) & 1u)) >> 16;   // RNE
}
__device__ __forceinline__ float bf_lo(unsigned int p) { return __uint_as_float(p << 16); }
__device__ __forceinline__ float bf_hi(unsigned int p) { return __uint_as_float(p & 0xffff0000u); }

// ---------- pass 1: per-edge slot reservation (the ONLY atomic pass) ----------
// cursor (pre-zeroed) ends up holding the in-degree of every node.
__global__ __launch_bounds__(256) void k_slot(const int* __restrict__ col,
                                              int* __restrict__ cursor,
                                              unsigned short* __restrict__ slot, int E) {
    int i = blockIdx.x * 256 + threadIdx.x;
    int base = i * 2;
    if (base + 1 < E) {
        int2 c = *reinterpret_cast<const int2*>(col + base);
        unsigned short s0 = (unsigned short)atomicAdd(&cursor[c.x], 1);
        unsigned short s1 = (unsigned short)atomicAdd(&cursor[c.y], 1);
        ushort2 sv; sv.x = s0; sv.y = s1;
        *reinterpret_cast<ushort2*>(slot + base) = sv;
    } else if (base < E) {
        slot[base] = (unsigned short)atomicAdd(&cursor[col[base]], 1);
    }
}

// ---------- scan of deg (=cursor) -> exclusive ptr, plus dinv = rsqrt(deg+1) ----------
__global__ __launch_bounds__(1024) void k_scan1(const int* __restrict__ deg, int* __restrict__ ptr,
                                                int* __restrict__ bsum, float* __restrict__ dinv, int n) {
    __shared__ int s[SCAN_BLK];
    int t = threadIdx.x;
    int i = blockIdx.x * SCAN_BLK + t;
    int v = (i < n) ? deg[i] : 0;
    s[t] = v;
    __syncthreads();
    for (int off = 1; off < SCAN_BLK; off <<= 1) {
        int add = (t >= off) ? s[t - off] : 0;
        __syncthreads();
        s[t] += add;
        __syncthreads();
    }
    if (i < n) { ptr[i] = s[t] - v; dinv[i] = rsqrtf((float)(v + 1)); }
    if (t == SCAN_BLK - 1) bsum[blockIdx.x] = s[t];
}

__global__ __launch_bounds__(64) void k_scan2(int* __restrict__ bsum, int nb) {
    __shared__ int s[64];
    int t = threadIdx.x;
    int v = (t < nb) ? bsum[t] : 0;
    s[t] = v;
    __syncthreads();
    for (int off = 1; off < 64; off <<= 1) {
        int add = (t >= off) ? s[t - off] : 0;
        __syncthreads();
        s[t] += add;
        __syncthreads();
    }
    if (t < nb) bsum[t] = s[t] - v;
}

__global__ __launch_bounds__(256) void k_scan3(int* __restrict__ ptr, const int* __restrict__ bsum,
                                               int n, int E) {
    int i = blockIdx.x * 256 + threadIdx.x;
    if (i < n) ptr[i] += bsum[i / SCAN_BLK];
    if (i == 0) ptr[n] = E;
}

// ---------- pass 2: atomic-free CSR placement ----------
__global__ __launch_bounds__(256) void k_place(const int* __restrict__ row, const int* __restrict__ col,
                                               const int* __restrict__ ptr,
                                               const unsigned short* __restrict__ slot,
                                               int* __restrict__ csr_row, int E) {
    int i = blockIdx.x * 256 + threadIdx.x;
    int base = i * 2;
    if (base + 1 < E) {
        int2 r = *reinterpret_cast<const int2*>(row + base);
        int2 c = *reinterpret_cast<const int2*>(col + base);
        ushort2 s = *reinterpret_cast<const ushort2*>(slot + base);
        csr_row[ptr[c.x] + s.x] = r.x;
        csr_row[ptr[c.y] + s.y] = r.y;
    } else if (base < E) {
        csr_row[ptr[col[base]] + slot[base]] = row[base];
    }
}

// ---------- conversions: x->bf16 (plain and dinv-scaled), weights->fragment order ----------
__global__ __launch_bounds__(256) void k_convert(const float* __restrict__ x,
                                                 const float* __restrict__ dinv,
                                                 const float* __restrict__ Wg,
                                                 const float* __restrict__ Wr,
                                                 unsigned short* __restrict__ x_bf,
                                                 unsigned short* __restrict__ xs_bf,
                                                 unsigned short* __restrict__ wgf,
                                                 unsigned short* __restrict__ wrf,
                                                 int n) {
    int gid = blockIdx.x * 256 + threadIdx.x;
    int nx8 = n * (IN_C / 8);
    if (gid < nx8) {
        float dn = dinv[gid >> 4];
        const float4* xv = reinterpret_cast<const float4*>(x) + (size_t)gid * 2;
        float4 a = xv[0], b = xv[1];
        uint4 o, os;
        o.x  = f2bf(a.x) | (f2bf(a.y) << 16);
        o.y  = f2bf(a.z) | (f2bf(a.w) << 16);
        o.z  = f2bf(b.x) | (f2bf(b.y) << 16);
        o.w  = f2bf(b.z) | (f2bf(b.w) << 16);
        os.x = f2bf(a.x * dn) | (f2bf(a.y * dn) << 16);
        os.y = f2bf(a.z * dn) | (f2bf(a.w * dn) << 16);
        os.z = f2bf(b.x * dn) | (f2bf(b.y * dn) << 16);
        os.w = f2bf(b.z * dn) | (f2bf(b.w * dn) << 16);
        reinterpret_cast<uint4*>(x_bf)[gid]  = o;
        reinterpret_cast<uint4*>(xs_bf)[gid] = os;
    }
    if (gid < 8192) {  // weight fragments
        int wsel = gid >> 12;
        int u = gid & 4095;
        int ct = u >> 8, kt = (u >> 6) & 3, l = u & 63;
        int k0 = kt * 32 + (l >> 4) * 8;
        int colw = ct * 16 + (l & 15);
        const float* W = wsel ? Wr : Wg;
        unsigned short* Wf = wsel ? wrf : wgf;
        uint4 o;
        unsigned int s[8];
#pragma unroll
        for (int e = 0; e < 8; ++e) s[e] = f2bf(W[(size_t)(k0 + e) * OUT_C + colw]);
        o.x = s[0] | (s[1] << 16); o.y = s[2] | (s[3] << 16);
        o.z = s[4] | (s[5] << 16); o.w = s[6] | (s[7] << 16);
        reinterpret_cast<uint4*>(Wf)[u] = o;
    }
}

// ---------- aggregation: agg[c] = dinv[c] * (xs[c] + sum_e xs[r]), unroll x8 ----------
__global__ __launch_bounds__(256) void k_agg(const unsigned int* __restrict__ xs32,
                                             const float* __restrict__ dinv,
                                             const int* __restrict__ ptr,
                                             const int* __restrict__ csr_row,
                                             unsigned short* __restrict__ agg_bf, int n) {
    int c = blockIdx.x * 4 + (threadIdx.x >> 6);
    if (c >= n) return;
    int lane = threadIdx.x & 63;
    float dc = dinv[c];
    unsigned int p = xs32[(size_t)c * 64 + lane];
    float a0 = bf_lo(p), a1 = bf_hi(p);
    int e = ptr[c], end = ptr[c + 1];
    for (; e + 8 <= end; e += 8) {
        int r0 = csr_row[e],     r1 = csr_row[e + 1], r2 = csr_row[e + 2], r3 = csr_row[e + 3];
        int r4 = csr_row[e + 4], r5 = csr_row[e + 5], r6 = csr_row[e + 6], r7 = csr_row[e + 7];
        unsigned int q0 = xs32[(size_t)r0 * 64 + lane];
        unsigned int q1 = xs32[(size_t)r1 * 64 + lane];
        unsigned int q2 = xs32[(size_t)r2 * 64 + lane];
        unsigned int q3 = xs32[(size_t)r3 * 64 + lane];
        unsigned int q4 = xs32[(size_t)r4 * 64 + lane];
        unsigned int q5 = xs32[(size_t)r5 * 64 + lane];
        unsigned int q6 = xs32[(size_t)r6 * 64 + lane];
        unsigned int q7 = xs32[(size_t)r7 * 64 + lane];
        a0 += bf_lo(q0); a1 += bf_hi(q0);
        a0 += bf_lo(q1); a1 += bf_hi(q1);
        a0 += bf_lo(q2); a1 += bf_hi(q2);
        a0 += bf_lo(q3); a1 += bf_hi(q3);
        a0 += bf_lo(q4); a1 += bf_hi(q4);
        a0 += bf_lo(q5); a1 += bf_hi(q5);
        a0 += bf_lo(q6); a1 += bf_hi(q6);
        a0 += bf_lo(q7); a1 += bf_hi(q7);
    }
    for (; e < end; ++e) {
        unsigned int q = xs32[(size_t)csr_row[e] * 64 + lane];
        a0 += bf_lo(q); a1 += bf_hi(q);
    }
    a0 *= dc; a1 *= dc;
    *reinterpret_cast<unsigned int*>(agg_bf + (size_t)c * IN_C + lane * 2) = f2bf(a0) | (f2bf(a1) << 16);
}

// ---------- fused MFMA dual-GEMM + LayerNorm + ReLU + residual ----------
__global__ __launch_bounds__(256) void k_mfma(const unsigned short* __restrict__ agg_bf,
                                              const unsigned short* __restrict__ x_bf,
                                              const unsigned short* __restrict__ wgf,
                                              const unsigned short* __restrict__ wrf,
                                              const float* __restrict__ bgc,
                                              const float* __restrict__ gamma,
                                              const float* __restrict__ beta,
                                              const float* __restrict__ brc,
                                              float* __restrict__ out, int n) {
    int tid = threadIdx.x;
    int w = tid >> 6, l = tid & 63;
    int row0 = blockIdx.x * 32;
    int rtile = w & 1;
    int colhalf = (w >> 1) * 128;
    int g = l >> 4;

    int mrow = row0 + rtile * 16 + (l & 15);
    if (mrow >= n) mrow = n - 1;
    bf16x8 aagg[4], ax[4];
#pragma unroll
    for (int kt = 0; kt < 4; ++kt) {
        aagg[kt] = *reinterpret_cast<const bf16x8*>(agg_bf + (size_t)mrow * IN_C + kt * 32 + g * 8);
        ax[kt]   = *reinterpret_cast<const bf16x8*>(x_bf   + (size_t)mrow * IN_C + kt * 32 + g * 8);
    }

    f32x4 accg[8], accr[8];
#pragma unroll
    for (int ct = 0; ct < 8; ++ct) {
        accg[ct] = (f32x4){0.f, 0.f, 0.f, 0.f};
        accr[ct] = (f32x4){0.f, 0.f, 0.f, 0.f};
    }

#pragma unroll
    for (int ct = 0; ct < 8; ++ct) {
        int cg = (w >> 1) * 8 + ct;
#pragma unroll
        for (int kt = 0; kt < 4; ++kt) {
            bf16x8 bg_ = *reinterpret_cast<const bf16x8*>(wgf + ((size_t)(cg * 4 + kt) * 64 + l) * 8);
            bf16x8 br_ = *reinterpret_cast<const bf16x8*>(wrf + ((size_t)(cg * 4 + kt) * 64 + l) * 8);
            accg[ct] = __builtin_amdgcn_mfma_f32_16x16x32_bf16(aagg[kt], bg_, accg[ct], 0, 0, 0);
            accr[ct] = __builtin_amdgcn_mfma_f32_16x16x32_bf16(ax[kt],   br_, accr[ct], 0, 0, 0);
        }
    }

    float s1[4] = {0.f, 0.f, 0.f, 0.f}, s2[4] = {0.f, 0.f, 0.f, 0.f};
#pragma unroll
    for (int ct = 0; ct < 8; ++ct) {
        int colj = colhalf + ct * 16 + (l & 15);
        float b = bgc[colj];
#pragma unroll
        for (int r = 0; r < 4; ++r) {
            float v = accg[ct][r] + b;
            accg[ct][r] = v;
            s1[r] += v;
            s2[r] += v * v;
        }
    }
#pragma unroll
    for (int off = 1; off < 16; off <<= 1) {
#pragma unroll
        for (int r = 0; r < 4; ++r) {
            s1[r] += __shfl_xor(s1[r], off);
            s2[r] += __shfl_xor(s2[r], off);
        }
    }

    __shared__ float red1[4][16], red2[4][16];
    if ((l & 15) == 0) {
#pragma unroll
        for (int r = 0; r < 4; ++r) {
            red1[w][g * 4 + r] = s1[r];
            red2[w][g * 4 + r] = s2[r];
        }
    }
    __syncthreads();
    int wp = w ^ 2;
    float mu[4], rs[4];
#pragma unroll
    for (int r = 0; r < 4; ++r) {
        float t1 = s1[r] + red1[wp][g * 4 + r];
        float t2 = s2[r] + red2[wp][g * 4 + r];
        float m = t1 * (1.f / OUT_C);
        float var = t2 * (1.f / OUT_C) - m * m;
        mu[r] = m;
        rs[r] = rsqrtf(var + LN_EPS);
    }

#pragma unroll
    for (int ct = 0; ct < 8; ++ct) {
        int colj = colhalf + ct * 16 + (l & 15);
        float ga = gamma[colj], be = beta[colj], brv = brc[colj];
#pragma unroll
        for (int r = 0; r < 4; ++r) {
            int rown = row0 + rtile * 16 + g * 4 + r;
            if (rown < n) {
                float ln = (accg[ct][r] - mu[r]) * rs[r] * ga + be;
                float val = fmaxf(ln, 0.f) + accr[ct][r] + brv;
                out[(size_t)rown * OUT_C + colj] = val;
            }
        }
    }
}

extern "C" void kernel_launch(void* const* d_in, const int* in_sizes, int n_in,
                              void* d_out, int out_size, void* d_ws, size_t ws_size,
                              hipStream_t stream) {
    const float* x     = (const float*)d_in[0];
    const int*   ei    = (const int*)d_in[1];
    const float* Wg    = (const float*)d_in[2];
    const float* bg    = (const float*)d_in[3];
    const float* gamma = (const float*)d_in[4];
    const float* beta  = (const float*)d_in[5];
    const float* Wr    = (const float*)d_in[6];
    const float* br    = (const float*)d_in[7];
    float* out = (float*)d_out;

    int N = in_sizes[0] / IN_C;
    int E = in_sizes[1] / 2;
    const int* row = ei;
    const int* col = ei + E;

    char* ws = (char*)d_ws;
    size_t off = 0;
    auto alloc = [&](size_t bytes) -> void* {
        void* p = ws + off;
        off += (bytes + 255) & ~(size_t)255;
        return p;
    };
    unsigned short* x_bf   = (unsigned short*)alloc((size_t)N * IN_C * 2);
    unsigned short* xs_bf  = (unsigned short*)alloc((size_t)N * IN_C * 2);
    unsigned short* agg_bf = (unsigned short*)alloc((size_t)N * IN_C * 2);
    unsigned short* wgf    = (unsigned short*)alloc((size_t)IN_C * OUT_C * 2);
    unsigned short* wrf    = (unsigned short*)alloc((size_t)IN_C * OUT_C * 2);
    float* dinv    = (float*)alloc((size_t)N * sizeof(float));
    int*   cursor  = (int*)alloc((size_t)N * sizeof(int));   // becomes deg
    int*   ptr     = (int*)alloc((size_t)(N + 1) * sizeof(int));
    int*   bsum    = (int*)alloc(64 * sizeof(int));
    unsigned short* slot = (unsigned short*)alloc((size_t)E * sizeof(unsigned short));
    int*   csr_row = (int*)alloc((size_t)E * sizeof(int));
    (void)ws_size; (void)n_in; (void)out_size;

    int nbN  = (N + 255) / 256;
    int nbE2 = (E + 511) / 512;
    int nsb  = (N + SCAN_BLK - 1) / SCAN_BLK;
    int ncvt = (N * (IN_C / 8) + 255) / 256;

    hipMemsetAsync(cursor, 0, (size_t)N * sizeof(int), stream);
    k_slot   <<<nbE2, 256, 0, stream>>>(col, cursor, slot, E);
    k_scan1  <<<nsb, 1024, 0, stream>>>(cursor, ptr, bsum, dinv, N);
    k_scan2  <<<1, 64, 0, stream>>>(bsum, nsb);
    k_scan3  <<<nbN, 256, 0, stream>>>(ptr, bsum, N, E);
    k_place  <<<nbE2, 256, 0, stream>>>(row, col, ptr, slot, csr_row, E);
    k_convert<<<ncvt, 256, 0, stream>>>(x, dinv, Wg, Wr, x_bf, xs_bf, wgf, wrf, N);
    k_agg    <<<(N + 3) / 4, 256, 0, stream>>>((const unsigned int*)xs_bf, dinv, ptr, csr_row, agg_bf, N);
    k_mfma   <<<(N + 31) / 32, 256, 0, stream>>>(agg_bf, x_bf, wgf, wrf, bg, gamma, beta, br, out, N);
}